// Round 13
// baseline (69451.215 us; speedup 1.0000x reference)
//
#include <hip/hip_runtime.h>
#include <hip/hip_bf16.h>
#include <hip/hip_cooperative_groups.h>
#include <cstdint>

static constexpr int B_ = 256;
static constexpr int T_ = 512;
static constexpr int I_ = 64;
static constexpr int H_ = 512;
static constexpr int G_ = 2048;            // gate cols, col = 4*j + g
static constexpr int L_ = 4;

typedef __attribute__((ext_vector_type(8))) short short8;   // 8 bf16
typedef __attribute__((ext_vector_type(4))) float f32x4;
typedef __attribute__((ext_vector_type(4))) unsigned int u32x4;

__device__ __forceinline__ float bfu2f(unsigned short u) {
    return __uint_as_float(((unsigned int)u) << 16);
}
__device__ __forceinline__ unsigned short f2bfu(float v) {
    __hip_bfloat16 h = __float2bfloat16(v);   // RNE
    return *(unsigned short*)&h;
}

// ---------- weight prep: per-(layer, 32-col slice) B-frag layout, split hi/lo ----------
__global__ void prep_wtfrag(const float* __restrict__ Whh_l,
                            const float* __restrict__ Wih_l,
                            int Kin, int NKB,
                            unsigned short* __restrict__ WH,
                            unsigned short* __restrict__ WL)
{
    const size_t total = (size_t)(H_ + Kin) * G_;
    const size_t Sl = (size_t)2 * NKB * 512;
    for (size_t idx = (size_t)blockIdx.x * blockDim.x + threadIdx.x; idx < total;
         idx += (size_t)gridDim.x * blockDim.x) {
        const int k = (int)(idx >> 11);
        const int n = (int)(idx & 2047);
        const int j = n >> 2, g = n & 3;
        const int r = g * H_ + j;
        const float w = (k < H_) ? Whh_l[(size_t)r * H_ + k]
                                 : Wih_l[(size_t)r * Kin + (k - H_)];
        const int ns = n >> 5, ntl = (n >> 4) & 1, n16 = n & 15;
        const int kb = k >> 5, bq = (k >> 3) & 3, kk = k & 7;
        const size_t off = (size_t)ns * Sl
                         + ((size_t)(ntl * NKB + kb) * 64 + (n16 + (bq << 4))) * 8 + kk;
        const unsigned short hi = f2bfu(w);
        WH[off] = hi;
        WL[off] = f2bfu(w - bfu2f(hi));
    }
}

__global__ void prep_bias(const float* __restrict__ bih, const float* __restrict__ bhh,
                          float* __restrict__ biasR)
{
    const int idx = blockIdx.x * blockDim.x + threadIdx.x;
    if (idx < L_ * G_) {
        const int l   = idx >> 11;
        const int col = idx & 2047;
        const int j = col >> 2, g = col & 3;
        const int r = l * G_ + g * H_ + j;
        biasR[idx] = bih[r] + bhh[r];
    }
}

__global__ void sentinel_fill(float* out, float v) { out[threadIdx.x] = v; }

__device__ __forceinline__ void spin_ge(int* p, int target) {
    while (__hip_atomic_load(p, __ATOMIC_ACQUIRE, __HIP_MEMORY_SCOPE_AGENT) < target)
        __builtin_amdgcn_s_sleep(16);
}

// ---------- dataflow-synced 4-layer LSTM: LDS weights + per-layer done-counters ----------
// 256 blocks x 1024 threads, 128 KB dynamic LDS (weights), 1 block/CU.
// Block (l = blk>>6, cs = blk&63) owns gate cols [cs*32, cs*32+32) for ALL 256 batches.
// NO grid.sync: depth-D h-slot ring + done[l] counters (one atomicAdd per block per step).
//   Block at local step t waits: done[l] >= 64*t         (siblings past t-1)
//                                done[l-1] >= 64*(t+1)    (input h(t) ready; l>0)
//                                done[l+1] >= 64*(t-D+1)  (slot we overwrite consumed; l<3, t>=D)
// All waits target strictly earlier (layer,step) -> acyclic -> deadlock-free.
// bnd layout: [l][slot D][bc8][kb16][mt2][lane64][kk8];
//   write slot t&(D-1); own-h read slot (t-1)&(D-1); input read slot t&(D-1) of layer l-1.
__global__ __launch_bounds__(1024, 4)
void lstm_pipe(const float* __restrict__ x,
               const unsigned short* __restrict__ WH0, const unsigned short* __restrict__ WL0,
               const unsigned short* __restrict__ WH1, const unsigned short* __restrict__ WL1,
               const unsigned short* __restrict__ WH2, const unsigned short* __restrict__ WL2,
               const unsigned short* __restrict__ WH3, const unsigned short* __restrict__ WL3,
               const float* __restrict__ biasR,
               unsigned short* __restrict__ bndH, unsigned short* __restrict__ bndL,
               int D, int* __restrict__ done)
{
    extern __shared__ unsigned short wgt[];   // [split2][ntl2][kb32][lane64][kk8] = 131072 B

    const int tid = threadIdx.x;
    const int blk = blockIdx.x;
    const int l   = blk >> 6;
    const int cs  = blk & 63;
    const int lane = tid & 63;
    const int wv   = tid >> 6;           // 0..15
    const int bcw  = wv >> 1;            // batch chunk (32 rows)
    const int mtw  = wv & 1;

    const unsigned short* __restrict__ WHl = (l == 0) ? WH0 : (l == 1) ? WH1 : (l == 2) ? WH2 : WH3;
    const unsigned short* __restrict__ WLl = (l == 0) ? WL0 : (l == 1) ? WL1 : (l == 2) ? WL2 : WL3;
    const int NKB = (l == 0) ? 18 : 32;
    const int Dm = D - 1;

    // ---- one-time: copy this block's weight slice into LDS ----
    {
        const size_t gb = (size_t)cs * (2 * NKB * 512);
        const int chunks = 2 * NKB * 64;
        for (int c = tid; c < chunks; c += 1024) {
            const int ntl = c / (NKB * 64);
            const int r   = c - ntl * (NKB * 64);
            const int kb  = r >> 6, ln = r & 63;
            const size_t so = gb + ((size_t)(ntl * NKB + kb) * 64 + ln) * 8;
            const int dof = ((ntl * 32 + kb) * 64 + ln) * 8;
            *(u32x4*)&wgt[dof]         = *(const u32x4*)(WHl + so);
            *(u32x4*)&wgt[32768 + dof] = *(const u32x4*)(WLl + so);
        }
    }
    __syncthreads();

    // epilogue mapping (after 4x4 shfl transpose)
    const int dl  = lane & 3;
    const int u0  = (lane & 15) >> 2;
    const int row = bcw * 32 + mtw * 16 + ((lane >> 4) << 2) + dl;
    const int j0  = cs * 8 + u0;
    const int j1  = j0 + 4;
    const float4 bias0 = *(const float4*)(biasR + l * G_ + (j0 << 2));
    const float4 bias1 = *(const float4*)(biasR + l * G_ + (j1 << 2));
    const int bc2 = row >> 5, mt2 = (row >> 4) & 1, m16r = row & 15;
    auto h_eo = [&](int j) -> size_t {
        return (size_t)(j >> 5) * 1024 + (size_t)mt2 * 512
             + (size_t)(m16r + (((j >> 3) & 3) << 4)) * 8 + (j & 7);
    };
    const size_t eo0 = h_eo(j0), eo1 = h_eo(j1);

    auto xpose = [&](f32x4& v) {
        float t0 = __shfl_xor(v[1], 1);
        float t1 = __shfl_xor(v[0], 1);
        float t2 = __shfl_xor(v[3], 1);
        float t3 = __shfl_xor(v[2], 1);
        if (dl & 1) { v[0] = t0; v[2] = t2; } else { v[1] = t1; v[3] = t3; }
        float s0 = __shfl_xor(v[2], 2);
        float s1 = __shfl_xor(v[3], 2);
        float s2 = __shfl_xor(v[0], 2);
        float s3 = __shfl_xor(v[1], 2);
        if (dl & 2) { v[0] = s0; v[1] = s1; } else { v[2] = s2; v[3] = s3; }
    };

    float c0 = 0.f, c1 = 0.f;

    for (int t = 0; t < T_; ++t) {
        // ---- dataflow waits (tid 0 spins; others park at the barrier) ----
        if (tid == 0) {
            if (t > 0)            spin_ge(done + l * 32,        64 * t);
            if (l > 0)            spin_ge(done + (l - 1) * 32,  64 * (t + 1));
            if (l < 3 && t >= D)  spin_ge(done + (l + 1) * 32,  64 * (t - D + 1));
        }
        __syncthreads();

        const int sw = t & Dm;                  // write slot
        const int sr = (t - 1) & Dm;            // own-h read slot (t=0 -> D-1, zeroed)
        const size_t ebOwn = ((size_t)((l * D + sr) * 8 + bcw)) * 16384
                           + (size_t)mtw * 512 + (size_t)lane * 8;

        f32x4 C0 = {0.f, 0.f, 0.f, 0.f};
        f32x4 C1 = {0.f, 0.f, 0.f, 0.f};

        // ---- own h(t-1): kb slots 0..15 ----
        {
            const unsigned short* aH_ = bndH + ebOwn;
            const unsigned short* aL_ = bndL + ebOwn;
#pragma unroll 4
            for (int kbl = 0; kbl < 16; ++kbl) {
                const short8 aH = *(const short8*)(aH_ + kbl * 1024);
                const short8 aL = *(const short8*)(aL_ + kbl * 1024);
                const int wo = kbl * 512 + lane * 8;
                const short8 wH0 = *(const short8*)&wgt[wo];
                const short8 wL0 = *(const short8*)&wgt[32768 + wo];
                const short8 wH1 = *(const short8*)&wgt[16384 + wo];
                const short8 wL1 = *(const short8*)&wgt[49152 + wo];
                C0 = __builtin_amdgcn_mfma_f32_16x16x32_bf16(aH, wH0, C0, 0, 0, 0);
                C0 = __builtin_amdgcn_mfma_f32_16x16x32_bf16(aL, wH0, C0, 0, 0, 0);
                C0 = __builtin_amdgcn_mfma_f32_16x16x32_bf16(aH, wL0, C0, 0, 0, 0);
                C1 = __builtin_amdgcn_mfma_f32_16x16x32_bf16(aH, wH1, C1, 0, 0, 0);
                C1 = __builtin_amdgcn_mfma_f32_16x16x32_bf16(aL, wH1, C1, 0, 0, 0);
                C1 = __builtin_amdgcn_mfma_f32_16x16x32_bf16(aH, wL1, C1, 0, 0, 0);
            }
        }
        // ---- input part: kb slots 16.. ----
        if (l > 0) {
            const size_t ebIn = ((size_t)(((l - 1) * D + sw) * 8 + bcw)) * 16384
                              + (size_t)mtw * 512 + (size_t)lane * 8;
            const unsigned short* aH_ = bndH + ebIn;
            const unsigned short* aL_ = bndL + ebIn;
#pragma unroll 4
            for (int kbl = 0; kbl < 16; ++kbl) {
                const short8 aH = *(const short8*)(aH_ + kbl * 1024);
                const short8 aL = *(const short8*)(aL_ + kbl * 1024);
                const int wo = (16 + kbl) * 512 + lane * 8;
                const short8 wH0 = *(const short8*)&wgt[wo];
                const short8 wL0 = *(const short8*)&wgt[32768 + wo];
                const short8 wH1 = *(const short8*)&wgt[16384 + wo];
                const short8 wL1 = *(const short8*)&wgt[49152 + wo];
                C0 = __builtin_amdgcn_mfma_f32_16x16x32_bf16(aH, wH0, C0, 0, 0, 0);
                C0 = __builtin_amdgcn_mfma_f32_16x16x32_bf16(aL, wH0, C0, 0, 0, 0);
                C0 = __builtin_amdgcn_mfma_f32_16x16x32_bf16(aH, wL0, C0, 0, 0, 0);
                C1 = __builtin_amdgcn_mfma_f32_16x16x32_bf16(aH, wH1, C1, 0, 0, 0);
                C1 = __builtin_amdgcn_mfma_f32_16x16x32_bf16(aL, wH1, C1, 0, 0, 0);
                C1 = __builtin_amdgcn_mfma_f32_16x16x32_bf16(aH, wL1, C1, 0, 0, 0);
            }
        } else {
            const int rowa = bcw * 32 + mtw * 16 + (lane & 15);
            const float* xb = x + ((size_t)rowa * T_ + t) * I_ + ((lane >> 4) << 3);
#pragma unroll
            for (int kbl = 0; kbl < 2; ++kbl) {
                float xv[8];
                *(float4*)&xv[0] = *(const float4*)(xb + kbl * 32);
                *(float4*)&xv[4] = *(const float4*)(xb + kbl * 32 + 4);
                short8 aH, aL;
#pragma unroll
                for (int e = 0; e < 8; ++e) {
                    const unsigned short hi = f2bfu(xv[e]);
                    aH[e] = (short)hi;
                    aL[e] = (short)f2bfu(xv[e] - bfu2f(hi));
                }
                const int wo = (16 + kbl) * 512 + lane * 8;
                const short8 wH0 = *(const short8*)&wgt[wo];
                const short8 wL0 = *(const short8*)&wgt[32768 + wo];
                const short8 wH1 = *(const short8*)&wgt[16384 + wo];
                const short8 wL1 = *(const short8*)&wgt[49152 + wo];
                C0 = __builtin_amdgcn_mfma_f32_16x16x32_bf16(aH, wH0, C0, 0, 0, 0);
                C0 = __builtin_amdgcn_mfma_f32_16x16x32_bf16(aL, wH0, C0, 0, 0, 0);
                C0 = __builtin_amdgcn_mfma_f32_16x16x32_bf16(aH, wL0, C0, 0, 0, 0);
                C1 = __builtin_amdgcn_mfma_f32_16x16x32_bf16(aH, wH1, C1, 0, 0, 0);
                C1 = __builtin_amdgcn_mfma_f32_16x16x32_bf16(aL, wH1, C1, 0, 0, 0);
                C1 = __builtin_amdgcn_mfma_f32_16x16x32_bf16(aH, wL1, C1, 0, 0, 0);
            }
        }

        // ---- 4x4 transpose: lane -> (row, unit) with all 4 gates in regs ----
        xpose(C0);
        xpose(C1);

        // ---- gates -> c,h ; write h(t) ----
        const size_t wb = ((size_t)((l * D + sw) * 8 + bc2)) * 16384;
        {
            const float gi = C0[0] + bias0.x;
            const float gf = C0[1] + bias0.y;
            const float gg = C0[2] + bias0.z;
            const float go = C0[3] + bias0.w;
            const float iv = 1.f / (1.f + expf(-gi));
            const float fv = 1.f / (1.f + expf(-gf));
            const float gv = tanhf(gg);
            const float ov = 1.f / (1.f + expf(-go));
            c0 = fv * c0 + iv * gv;
            const float hv = ov * tanhf(c0);
            const unsigned short hi = f2bfu(hv);
            bndH[wb + eo0] = hi;
            bndL[wb + eo0] = f2bfu(hv - bfu2f(hi));
        }
        {
            const float gi = C1[0] + bias1.x;
            const float gf = C1[1] + bias1.y;
            const float gg = C1[2] + bias1.z;
            const float go = C1[3] + bias1.w;
            const float iv = 1.f / (1.f + expf(-gi));
            const float fv = 1.f / (1.f + expf(-gf));
            const float gv = tanhf(gg);
            const float ov = 1.f / (1.f + expf(-go));
            c1 = fv * c1 + iv * gv;
            const float hv = ov * tanhf(c1);
            const unsigned short hi = f2bfu(hv);
            bndH[wb + eo1] = hi;
            bndL[wb + eo1] = f2bfu(hv - bfu2f(hi));
        }

        // ---- publish: all writes/reads of this step done -> bump done[l] ----
        __threadfence();
        __syncthreads();
        if (tid == 0)
            __hip_atomic_fetch_add(done + l * 32, 1, __ATOMIC_RELEASE, __HIP_MEMORY_SCOPE_AGENT);
    }
}

// ---------- MLP head: reads h_3[T-1] from slot (T-1)&(D-1) ----------
__global__ __launch_bounds__(128)
void mlp_head(const unsigned short* __restrict__ bndH, const unsigned short* __restrict__ bndL,
              const float* __restrict__ W1, const float* __restrict__ b1,
              const float* __restrict__ W2, const float* __restrict__ b2,
              const float* __restrict__ W3, const float* __restrict__ b3,
              float* __restrict__ out, int D)
{
    __shared__ float hl[H_];
    __shared__ float a1[128];
    __shared__ float a2[64];
    const int b = blockIdx.x, tid = threadIdx.x;
    {
        const int bc = b >> 5, m = b & 31;
        const int mtt = m >> 4, m16 = m & 15;
        const size_t base = ((size_t)((3 * D + ((T_ - 1) & (D - 1))) * 8 + bc)) * 16384;
        const int k0 = tid << 2;
        const int kb = k0 >> 5, bq = (k0 >> 3) & 3, kk0 = k0 & 7;
        const size_t eo = base + ((size_t)((kb << 1) + mtt) * 64 + (m16 + (bq << 4))) * 8 + kk0;
        const ushort4 vh = *(const ushort4*)(bndH + eo);
        const ushort4 vl = *(const ushort4*)(bndL + eo);
        hl[k0 + 0] = bfu2f(vh.x) + bfu2f(vl.x);
        hl[k0 + 1] = bfu2f(vh.y) + bfu2f(vl.y);
        hl[k0 + 2] = bfu2f(vh.z) + bfu2f(vl.z);
        hl[k0 + 3] = bfu2f(vh.w) + bfu2f(vl.w);
    }
    __syncthreads();
    {
        float s = b1[tid];
        const float* wr = W1 + (size_t)tid * H_;
        for (int k = 0; k < H_; ++k) s = fmaf(wr[k], hl[k], s);
        a1[tid] = fmaxf(s, 0.f);
    }
    __syncthreads();
    if (tid < 64) {
        float s = b2[tid];
        const float* wr = W2 + (tid << 7);
        for (int k = 0; k < 128; ++k) s = fmaf(wr[k], a1[k], s);
        a2[tid] = fmaxf(s, 0.f);
    }
    __syncthreads();
    if (tid < 64) {
        float v = W3[tid] * a2[tid];
        for (int off = 32; off; off >>= 1) v += __shfl_down(v, off);
        if (tid == 0) out[b] = v + b3[0];
    }
}

extern "C" void kernel_launch(void* const* d_in, const int* in_sizes, int n_in,
                              void* d_out, int out_size, void* d_ws, size_t ws_size,
                              hipStream_t stream)
{
    const float* x    = (const float*)d_in[0];
    const float* Wih0 = (const float*)d_in[1];
    const float* WihR = (const float*)d_in[2];
    const float* Whh  = (const float*)d_in[3];
    const float* bih  = (const float*)d_in[4];
    const float* bhh  = (const float*)d_in[5];
    const float* W1   = (const float*)d_in[6];
    const float* b1   = (const float*)d_in[7];
    const float* W2   = (const float*)d_in[8];
    const float* b2   = (const float*)d_in[9];
    const float* W3   = (const float*)d_in[10];
    const float* b3   = (const float*)d_in[11];
    float* out = (float*)d_out;

    const size_t W0e = (size_t)(H_ + I_) * G_;
    const size_t W1e = (size_t)(2 * H_) * G_;
    const size_t biasE = (size_t)L_ * G_;

    auto align256 = [](size_t v) { return (v + 255) & ~(size_t)255; };
    const size_t wfix = 2 * align256(W0e * 2) + 6 * align256(W1e * 2)
                      + align256(biasE * 4) + align256(L_ * 32 * sizeof(int));
    auto bndElems = [](int D) { return (size_t)L_ * D * 8 * 16384; };

    int D = 4;
    if (ws_size < wfix + 2 * align256(bndElems(4) * 2)) D = 2;
    if (ws_size < wfix + 2 * align256(bndElems(2) * 2)) {
        sentinel_fill<<<1, 256, 0, stream>>>(out, -11111.0f);
        return;
    }
    const size_t bndE = bndElems(D);

    char* ws = (char*)d_ws;
    size_t off = 0;
    auto alloc = [&](size_t bytes) -> void* {
        void* p = ws + off;
        off = align256(off + bytes);
        return p;
    };

    unsigned short* WH0 = (unsigned short*)alloc(W0e * 2);
    unsigned short* WL0 = (unsigned short*)alloc(W0e * 2);
    unsigned short* WH1 = (unsigned short*)alloc(W1e * 2);
    unsigned short* WL1 = (unsigned short*)alloc(W1e * 2);
    unsigned short* WH2 = (unsigned short*)alloc(W1e * 2);
    unsigned short* WL2 = (unsigned short*)alloc(W1e * 2);
    unsigned short* WH3 = (unsigned short*)alloc(W1e * 2);
    unsigned short* WL3 = (unsigned short*)alloc(W1e * 2);
    float* biasR = (float*)alloc(biasE * 4);
    int* done    = (int*)alloc(L_ * 32 * sizeof(int));
    unsigned short* bndH = (unsigned short*)alloc(bndE * 2);
    unsigned short* bndL = (unsigned short*)alloc(bndE * 2);

    const size_t WL_ = (size_t)G_ * H_;
    prep_wtfrag<<<1024, 256, 0, stream>>>(Whh + 0 * WL_, Wih0,           I_, 18, WH0, WL0);
    prep_wtfrag<<<1024, 256, 0, stream>>>(Whh + 1 * WL_, WihR + 0 * WL_, H_, 32, WH1, WL1);
    prep_wtfrag<<<1024, 256, 0, stream>>>(Whh + 2 * WL_, WihR + 1 * WL_, H_, 32, WH2, WL2);
    prep_wtfrag<<<1024, 256, 0, stream>>>(Whh + 3 * WL_, WihR + 2 * WL_, H_, 32, WH3, WL3);
    prep_bias<<<(L_ * G_ + 255) / 256, 256, 0, stream>>>(bih, bhh, biasR);
    (void)hipMemsetAsync(done, 0, L_ * 32 * sizeof(int), stream);
    (void)hipMemsetAsync(bndH, 0, bndE * 2, stream);
    (void)hipMemsetAsync(bndL, 0, bndE * 2, stream);

    {
        (void)hipFuncSetAttribute((const void*)lstm_pipe,
                                  hipFuncAttributeMaxDynamicSharedMemorySize, 131072);
        const float* xa = x;
        const unsigned short *a0 = WH0, *a1 = WL0, *a2 = WH1, *a3 = WL1,
                             *a4 = WH2, *a5 = WL2, *a6 = WH3, *a7 = WL3;
        const float* br = biasR;
        unsigned short *bh = bndH, *bl = bndL;
        int Dv = D; int* dn = done;
        void* args[] = { (void*)&xa, (void*)&a0, (void*)&a1, (void*)&a2, (void*)&a3,
                         (void*)&a4, (void*)&a5, (void*)&a6, (void*)&a7,
                         (void*)&br, (void*)&bh, (void*)&bl, (void*)&Dv, (void*)&dn };
        hipError_t rc = hipLaunchCooperativeKernel((void*)lstm_pipe, dim3(256), dim3(1024),
                                                   args, 131072, stream);
        if (rc != hipSuccess) {
            sentinel_fill<<<1, 256, 0, stream>>>(out, -22222.0f);
            return;
        }
    }

    mlp_head<<<256, 128, 0, stream>>>(bndH, bndL, W1, b1, W2, b2, W3, b3, out, D);
}

// Round 14
// 22900.215 us; speedup vs baseline: 3.0328x; 3.0328x over previous
//
#include <hip/hip_runtime.h>
#include <hip/hip_bf16.h>
#include <hip/hip_cooperative_groups.h>
#include <cstdint>

namespace cg = cooperative_groups;

static constexpr int B_ = 256;
static constexpr int T_ = 512;
static constexpr int I_ = 64;
static constexpr int H_ = 512;
static constexpr int G_ = 2048;            // gate cols, col = 4*j + g
static constexpr int L_ = 4;
static constexpr int NSTEP = T_ + L_ - 1;  // 515

typedef __attribute__((ext_vector_type(8))) short short8;   // 8 bf16
typedef __attribute__((ext_vector_type(4))) float f32x4;
typedef __attribute__((ext_vector_type(4))) unsigned int u32x4;

__device__ __forceinline__ float bfu2f(unsigned short u) {
    return __uint_as_float(((unsigned int)u) << 16);
}
__device__ __forceinline__ unsigned short f2bfu(float v) {
    __hip_bfloat16 h = __float2bfloat16(v);   // RNE
    return *(unsigned short*)&h;
}

// ---------- weight prep: per-(layer, 32-col slice) B-frag layout, split hi/lo ----------
__global__ void prep_wtfrag(const float* __restrict__ Whh_l,
                            const float* __restrict__ Wih_l,
                            int Kin, int NKB,
                            unsigned short* __restrict__ WH,
                            unsigned short* __restrict__ WL)
{
    const size_t total = (size_t)(H_ + Kin) * G_;
    const size_t Sl = (size_t)2 * NKB * 512;
    for (size_t idx = (size_t)blockIdx.x * blockDim.x + threadIdx.x; idx < total;
         idx += (size_t)gridDim.x * blockDim.x) {
        const int k = (int)(idx >> 11);
        const int n = (int)(idx & 2047);
        const int j = n >> 2, g = n & 3;
        const int r = g * H_ + j;
        const float w = (k < H_) ? Whh_l[(size_t)r * H_ + k]
                                 : Wih_l[(size_t)r * Kin + (k - H_)];
        const int ns = n >> 5, ntl = (n >> 4) & 1, n16 = n & 15;
        const int kb = k >> 5, bq = (k >> 3) & 3, kk = k & 7;
        const size_t off = (size_t)ns * Sl
                         + ((size_t)(ntl * NKB + kb) * 64 + (n16 + (bq << 4))) * 8 + kk;
        const unsigned short hi = f2bfu(w);
        WH[off] = hi;
        WL[off] = f2bfu(w - bfu2f(hi));
    }
}

__global__ void prep_bias(const float* __restrict__ bih, const float* __restrict__ bhh,
                          float* __restrict__ biasR)
{
    const int idx = blockIdx.x * blockDim.x + threadIdx.x;
    if (idx < L_ * G_) {
        const int l   = idx >> 11;
        const int col = idx & 2047;
        const int j = col >> 2, g = col & 3;
        const int r = l * G_ + g * H_ + j;
        biasR[idx] = bih[r] + bhh[r];
    }
}

__global__ void sentinel_fill(float* out, float v) { out[threadIdx.x] = v; }

// ---------- pipelined 4-layer LSTM: LDS-resident weights, fused dual-K-stream ----------
// 256 blocks x 1024 threads, 128 KB dynamic LDS -> 1 block/CU. (= round-12 structure,
// which measured 22.1 ms; round-13's per-block flag sync was 3x slower — reverted.)
// Block (l = blk>>6, cs = blk&63) owns gate cols [cs*32, cs*32+32), all 256 batches.
// Per step, per wave: fused loop over 16 kbl, each iter = 4 A-loads (own h + input h,
// hi/lo) + 12 MFMAs -> single latency chain, ~16 loads in flight at unroll 4.
// bnd layout: [l][parity][bc8][kb16][mt2][lane64][kk8],
//   elem off = ((l*2+p)*8 + bc)*16384 + kb*1024 + mt*512 + lane*8 + kk.
// Step s: layer l computes t=s-l; reads parity (s+1)&1, writes parity s&1; 1 grid.sync/step.
__global__ __launch_bounds__(1024, 4)
void lstm_pipe(const float* __restrict__ x,
               const unsigned short* __restrict__ WH0, const unsigned short* __restrict__ WL0,
               const unsigned short* __restrict__ WH1, const unsigned short* __restrict__ WL1,
               const unsigned short* __restrict__ WH2, const unsigned short* __restrict__ WL2,
               const unsigned short* __restrict__ WH3, const unsigned short* __restrict__ WL3,
               const float* __restrict__ biasR,
               unsigned short* __restrict__ bndH, unsigned short* __restrict__ bndL)
{
    cg::grid_group grid = cg::this_grid();
    extern __shared__ unsigned short wgt[];   // [split2][ntl2][kb32][lane64][kk8] = 131072 B

    const int tid = threadIdx.x;
    const int blk = blockIdx.x;
    const int l   = blk >> 6;
    const int cs  = blk & 63;
    const int lane = tid & 63;
    const int wv   = tid >> 6;           // 0..15
    const int bcw  = wv >> 1;            // batch chunk (32 rows)
    const int mtw  = wv & 1;

    const unsigned short* __restrict__ WHl = (l == 0) ? WH0 : (l == 1) ? WH1 : (l == 2) ? WH2 : WH3;
    const unsigned short* __restrict__ WLl = (l == 0) ? WL0 : (l == 1) ? WL1 : (l == 2) ? WL2 : WL3;
    const int NKB = (l == 0) ? 18 : 32;

    // ---- one-time: copy this block's weight slice into LDS ----
    {
        const size_t gb = (size_t)cs * (2 * NKB * 512);
        const int chunks = 2 * NKB * 64;
        for (int c = tid; c < chunks; c += 1024) {
            const int ntl = c / (NKB * 64);
            const int r   = c - ntl * (NKB * 64);
            const int kb  = r >> 6, ln = r & 63;
            const size_t so = gb + ((size_t)(ntl * NKB + kb) * 64 + ln) * 8;
            const int dof = ((ntl * 32 + kb) * 64 + ln) * 8;
            *(u32x4*)&wgt[dof]         = *(const u32x4*)(WHl + so);
            *(u32x4*)&wgt[32768 + dof] = *(const u32x4*)(WLl + so);
        }
    }
    __syncthreads();

    // epilogue mapping (after 4x4 shfl transpose)
    const int dl  = lane & 3;
    const int u0  = (lane & 15) >> 2;
    const int row = bcw * 32 + mtw * 16 + ((lane >> 4) << 2) + dl;
    const int j0  = cs * 8 + u0;
    const int j1  = j0 + 4;
    const float4 bias0 = *(const float4*)(biasR + l * G_ + (j0 << 2));
    const float4 bias1 = *(const float4*)(biasR + l * G_ + (j1 << 2));
    const int bc2 = row >> 5, mt2 = (row >> 4) & 1, m16r = row & 15;
    auto h_eo = [&](int j) -> size_t {
        return (size_t)(j >> 5) * 1024 + (size_t)mt2 * 512
             + (size_t)(m16r + (((j >> 3) & 3) << 4)) * 8 + (j & 7);
    };
    const size_t eo0 = h_eo(j0), eo1 = h_eo(j1);

    auto xpose = [&](f32x4& v) {
        float t0 = __shfl_xor(v[1], 1);
        float t1 = __shfl_xor(v[0], 1);
        float t2 = __shfl_xor(v[3], 1);
        float t3 = __shfl_xor(v[2], 1);
        if (dl & 1) { v[0] = t0; v[2] = t2; } else { v[1] = t1; v[3] = t3; }
        float s0 = __shfl_xor(v[2], 2);
        float s1 = __shfl_xor(v[3], 2);
        float s2 = __shfl_xor(v[0], 2);
        float s3 = __shfl_xor(v[1], 2);
        if (dl & 2) { v[0] = s0; v[1] = s1; } else { v[2] = s2; v[3] = s3; }
    };

    float c0 = 0.f, c1 = 0.f;

    for (int s = 0; s < NSTEP; ++s) {
        const int t = s - l;
        if (0 <= t && t < T_) {
            const int pr = (s + 1) & 1;
            const int pw = s & 1;
            const size_t ebOwn = ((size_t)(l * 2 + pr) * 8 + bcw) * 16384
                               + (size_t)mtw * 512 + (size_t)lane * 8;

            f32x4 C0 = {0.f, 0.f, 0.f, 0.f};
            f32x4 C1 = {0.f, 0.f, 0.f, 0.f};

            if (l > 0) {
                const size_t ebIn = ((size_t)((l - 1) * 2 + pr) * 8 + bcw) * 16384
                                  + (size_t)mtw * 512 + (size_t)lane * 8;
                const unsigned short* aHo = bndH + ebOwn;
                const unsigned short* aLo = bndL + ebOwn;
                const unsigned short* aHi = bndH + ebIn;
                const unsigned short* aLi = bndL + ebIn;
                // fused dual-stream loop: 4 A-loads + 12 MFMAs per iter
#pragma unroll 4
                for (int kbl = 0; kbl < 16; ++kbl) {
                    const short8 a0H = *(const short8*)(aHo + kbl * 1024);
                    const short8 a0L = *(const short8*)(aLo + kbl * 1024);
                    const short8 a1H = *(const short8*)(aHi + kbl * 1024);
                    const short8 a1L = *(const short8*)(aLi + kbl * 1024);
                    const int wo0 = kbl * 512 + lane * 8;
                    const int wo1 = (16 + kbl) * 512 + lane * 8;
                    const short8 wH0o = *(const short8*)&wgt[wo0];
                    const short8 wL0o = *(const short8*)&wgt[32768 + wo0];
                    const short8 wH1o = *(const short8*)&wgt[16384 + wo0];
                    const short8 wL1o = *(const short8*)&wgt[49152 + wo0];
                    const short8 wH0i = *(const short8*)&wgt[wo1];
                    const short8 wL0i = *(const short8*)&wgt[32768 + wo1];
                    const short8 wH1i = *(const short8*)&wgt[16384 + wo1];
                    const short8 wL1i = *(const short8*)&wgt[49152 + wo1];
                    C0 = __builtin_amdgcn_mfma_f32_16x16x32_bf16(a0H, wH0o, C0, 0, 0, 0);
                    C0 = __builtin_amdgcn_mfma_f32_16x16x32_bf16(a0L, wH0o, C0, 0, 0, 0);
                    C0 = __builtin_amdgcn_mfma_f32_16x16x32_bf16(a0H, wL0o, C0, 0, 0, 0);
                    C1 = __builtin_amdgcn_mfma_f32_16x16x32_bf16(a0H, wH1o, C1, 0, 0, 0);
                    C1 = __builtin_amdgcn_mfma_f32_16x16x32_bf16(a0L, wH1o, C1, 0, 0, 0);
                    C1 = __builtin_amdgcn_mfma_f32_16x16x32_bf16(a0H, wL1o, C1, 0, 0, 0);
                    C0 = __builtin_amdgcn_mfma_f32_16x16x32_bf16(a1H, wH0i, C0, 0, 0, 0);
                    C0 = __builtin_amdgcn_mfma_f32_16x16x32_bf16(a1L, wH0i, C0, 0, 0, 0);
                    C0 = __builtin_amdgcn_mfma_f32_16x16x32_bf16(a1H, wL0i, C0, 0, 0, 0);
                    C1 = __builtin_amdgcn_mfma_f32_16x16x32_bf16(a1H, wH1i, C1, 0, 0, 0);
                    C1 = __builtin_amdgcn_mfma_f32_16x16x32_bf16(a1L, wH1i, C1, 0, 0, 0);
                    C1 = __builtin_amdgcn_mfma_f32_16x16x32_bf16(a1H, wL1i, C1, 0, 0, 0);
                }
            } else {
                // hoist x(t) loads (independent of this step's h) so they issue early
                const int rowa = bcw * 32 + mtw * 16 + (lane & 15);
                const float* xb = x + ((size_t)rowa * T_ + t) * I_ + ((lane >> 4) << 3);
                float4 xf0 = *(const float4*)(xb);
                float4 xf1 = *(const float4*)(xb + 4);
                float4 xf2 = *(const float4*)(xb + 32);
                float4 xf3 = *(const float4*)(xb + 36);

                const unsigned short* aHo = bndH + ebOwn;
                const unsigned short* aLo = bndL + ebOwn;
#pragma unroll 4
                for (int kbl = 0; kbl < 16; ++kbl) {
                    const short8 a0H = *(const short8*)(aHo + kbl * 1024);
                    const short8 a0L = *(const short8*)(aLo + kbl * 1024);
                    const int wo0 = kbl * 512 + lane * 8;
                    const short8 wH0o = *(const short8*)&wgt[wo0];
                    const short8 wL0o = *(const short8*)&wgt[32768 + wo0];
                    const short8 wH1o = *(const short8*)&wgt[16384 + wo0];
                    const short8 wL1o = *(const short8*)&wgt[49152 + wo0];
                    C0 = __builtin_amdgcn_mfma_f32_16x16x32_bf16(a0H, wH0o, C0, 0, 0, 0);
                    C0 = __builtin_amdgcn_mfma_f32_16x16x32_bf16(a0L, wH0o, C0, 0, 0, 0);
                    C0 = __builtin_amdgcn_mfma_f32_16x16x32_bf16(a0H, wL0o, C0, 0, 0, 0);
                    C1 = __builtin_amdgcn_mfma_f32_16x16x32_bf16(a0H, wH1o, C1, 0, 0, 0);
                    C1 = __builtin_amdgcn_mfma_f32_16x16x32_bf16(a0L, wH1o, C1, 0, 0, 0);
                    C1 = __builtin_amdgcn_mfma_f32_16x16x32_bf16(a0H, wL1o, C1, 0, 0, 0);
                }
                // x part: kb slots 16,17
                float xv[16];
                *(float4*)&xv[0]  = xf0;  *(float4*)&xv[4]  = xf1;
                *(float4*)&xv[8]  = xf2;  *(float4*)&xv[12] = xf3;
#pragma unroll
                for (int kbl = 0; kbl < 2; ++kbl) {
                    short8 aH, aL;
#pragma unroll
                    for (int e = 0; e < 8; ++e) {
                        const float v = xv[kbl * 8 + e];
                        const unsigned short hi = f2bfu(v);
                        aH[e] = (short)hi;
                        aL[e] = (short)f2bfu(v - bfu2f(hi));
                    }
                    const int wo = (16 + kbl) * 512 + lane * 8;
                    const short8 wH0 = *(const short8*)&wgt[wo];
                    const short8 wL0 = *(const short8*)&wgt[32768 + wo];
                    const short8 wH1 = *(const short8*)&wgt[16384 + wo];
                    const short8 wL1 = *(const short8*)&wgt[49152 + wo];
                    C0 = __builtin_amdgcn_mfma_f32_16x16x32_bf16(aH, wH0, C0, 0, 0, 0);
                    C0 = __builtin_amdgcn_mfma_f32_16x16x32_bf16(aL, wH0, C0, 0, 0, 0);
                    C0 = __builtin_amdgcn_mfma_f32_16x16x32_bf16(aH, wL0, C0, 0, 0, 0);
                    C1 = __builtin_amdgcn_mfma_f32_16x16x32_bf16(aH, wH1, C1, 0, 0, 0);
                    C1 = __builtin_amdgcn_mfma_f32_16x16x32_bf16(aL, wH1, C1, 0, 0, 0);
                    C1 = __builtin_amdgcn_mfma_f32_16x16x32_bf16(aH, wL1, C1, 0, 0, 0);
                }
            }

            // ---- 4x4 transpose: lane -> (row, unit) with all 4 gates in regs ----
            xpose(C0);
            xpose(C1);

            // ---- gates -> c,h ; write h(t) ----
            const size_t wb = ((size_t)(l * 2 + pw) * 8 + bc2) * 16384;
            {
                const float gi = C0[0] + bias0.x;
                const float gf = C0[1] + bias0.y;
                const float gg = C0[2] + bias0.z;
                const float go = C0[3] + bias0.w;
                const float iv = 1.f / (1.f + expf(-gi));
                const float fv = 1.f / (1.f + expf(-gf));
                const float gv = tanhf(gg);
                const float ov = 1.f / (1.f + expf(-go));
                c0 = fv * c0 + iv * gv;
                const float hv = ov * tanhf(c0);
                const unsigned short hi = f2bfu(hv);
                bndH[wb + eo0] = hi;
                bndL[wb + eo0] = f2bfu(hv - bfu2f(hi));
            }
            {
                const float gi = C1[0] + bias1.x;
                const float gf = C1[1] + bias1.y;
                const float gg = C1[2] + bias1.z;
                const float go = C1[3] + bias1.w;
                const float iv = 1.f / (1.f + expf(-gi));
                const float fv = 1.f / (1.f + expf(-gf));
                const float gv = tanhf(gg);
                const float ov = 1.f / (1.f + expf(-go));
                c1 = fv * c1 + iv * gv;
                const float hv = ov * tanhf(c1);
                const unsigned short hi = f2bfu(hv);
                bndH[wb + eo1] = hi;
                bndL[wb + eo1] = f2bfu(hv - bfu2f(hi));
            }
        }
        if (s != NSTEP - 1) grid.sync();   // final sync unneeded: kernel end is a release
    }
}

// ---------- MLP head: reads h_3[T-1] (parity 0) from bnd frag layout ----------
__global__ __launch_bounds__(128)
void mlp_head(const unsigned short* __restrict__ bndH, const unsigned short* __restrict__ bndL,
              const float* __restrict__ W1, const float* __restrict__ b1,
              const float* __restrict__ W2, const float* __restrict__ b2,
              const float* __restrict__ W3, const float* __restrict__ b3,
              float* __restrict__ out)
{
    __shared__ float hl[H_];
    __shared__ float a1[128];
    __shared__ float a2[64];
    const int b = blockIdx.x, tid = threadIdx.x;
    {
        const int bc = b >> 5, m = b & 31;
        const int mtt = m >> 4, m16 = m & 15;
        const size_t base = ((size_t)48 + bc) * 16384;   // (3*2+0)*8 + bc
        const int k0 = tid << 2;
        const int kb = k0 >> 5, bq = (k0 >> 3) & 3, kk0 = k0 & 7;
        const size_t eo = base + ((size_t)((kb << 1) + mtt) * 64 + (m16 + (bq << 4))) * 8 + kk0;
        const ushort4 vh = *(const ushort4*)(bndH + eo);
        const ushort4 vl = *(const ushort4*)(bndL + eo);
        hl[k0 + 0] = bfu2f(vh.x) + bfu2f(vl.x);
        hl[k0 + 1] = bfu2f(vh.y) + bfu2f(vl.y);
        hl[k0 + 2] = bfu2f(vh.z) + bfu2f(vl.z);
        hl[k0 + 3] = bfu2f(vh.w) + bfu2f(vl.w);
    }
    __syncthreads();
    {
        float s = b1[tid];
        const float* wr = W1 + (size_t)tid * H_;
        for (int k = 0; k < H_; ++k) s = fmaf(wr[k], hl[k], s);
        a1[tid] = fmaxf(s, 0.f);
    }
    __syncthreads();
    if (tid < 64) {
        float s = b2[tid];
        const float* wr = W2 + (tid << 7);
        for (int k = 0; k < 128; ++k) s = fmaf(wr[k], a1[k], s);
        a2[tid] = fmaxf(s, 0.f);
    }
    __syncthreads();
    if (tid < 64) {
        float v = W3[tid] * a2[tid];
        for (int off = 32; off; off >>= 1) v += __shfl_down(v, off);
        if (tid == 0) out[b] = v + b3[0];
    }
}

extern "C" void kernel_launch(void* const* d_in, const int* in_sizes, int n_in,
                              void* d_out, int out_size, void* d_ws, size_t ws_size,
                              hipStream_t stream)
{
    const float* x    = (const float*)d_in[0];
    const float* Wih0 = (const float*)d_in[1];
    const float* WihR = (const float*)d_in[2];
    const float* Whh  = (const float*)d_in[3];
    const float* bih  = (const float*)d_in[4];
    const float* bhh  = (const float*)d_in[5];
    const float* W1   = (const float*)d_in[6];
    const float* b1   = (const float*)d_in[7];
    const float* W2   = (const float*)d_in[8];
    const float* b2   = (const float*)d_in[9];
    const float* W3   = (const float*)d_in[10];
    const float* b3   = (const float*)d_in[11];
    float* out = (float*)d_out;

    const size_t W0e = (size_t)(H_ + I_) * G_;       // 1,179,648 elems (NKB=18)
    const size_t W1e = (size_t)(2 * H_) * G_;        // 2,097,152 elems (NKB=32)
    const size_t biasE = (size_t)L_ * G_;            // 8192
    const size_t bndE  = (size_t)64 * 16384;         // 1,048,576 elems per split

    auto align256 = [](size_t v) { return (v + 255) & ~(size_t)255; };
    const size_t need = 2 * align256(W0e * 2) + 6 * align256(W1e * 2)
                      + align256(biasE * 4) + 2 * align256(bndE * 2);

    char* ws = (char*)d_ws;
    size_t off = 0;
    auto alloc = [&](size_t bytes) -> void* {
        void* p = ws + off;
        off = align256(off + bytes);
        return p;
    };

    if (ws_size < need) {
        sentinel_fill<<<1, 256, 0, stream>>>(out, -11111.0f);
        return;
    }

    unsigned short* WH0 = (unsigned short*)alloc(W0e * 2);
    unsigned short* WL0 = (unsigned short*)alloc(W0e * 2);
    unsigned short* WH1 = (unsigned short*)alloc(W1e * 2);
    unsigned short* WL1 = (unsigned short*)alloc(W1e * 2);
    unsigned short* WH2 = (unsigned short*)alloc(W1e * 2);
    unsigned short* WL2 = (unsigned short*)alloc(W1e * 2);
    unsigned short* WH3 = (unsigned short*)alloc(W1e * 2);
    unsigned short* WL3 = (unsigned short*)alloc(W1e * 2);
    float* biasR = (float*)alloc(biasE * 4);
    unsigned short* bndH = (unsigned short*)alloc(bndE * 2);
    unsigned short* bndL = (unsigned short*)alloc(bndE * 2);

    const size_t WL_ = (size_t)G_ * H_;
    prep_wtfrag<<<1024, 256, 0, stream>>>(Whh + 0 * WL_, Wih0,           I_, 18, WH0, WL0);
    prep_wtfrag<<<1024, 256, 0, stream>>>(Whh + 1 * WL_, WihR + 0 * WL_, H_, 32, WH1, WL1);
    prep_wtfrag<<<1024, 256, 0, stream>>>(Whh + 2 * WL_, WihR + 1 * WL_, H_, 32, WH2, WL2);
    prep_wtfrag<<<1024, 256, 0, stream>>>(Whh + 3 * WL_, WihR + 2 * WL_, H_, 32, WH3, WL3);
    prep_bias<<<(L_ * G_ + 255) / 256, 256, 0, stream>>>(bih, bhh, biasR);
    (void)hipMemsetAsync(bndH, 0, bndE * 2, stream);
    (void)hipMemsetAsync(bndL, 0, bndE * 2, stream);

    {
        (void)hipFuncSetAttribute((const void*)lstm_pipe,
                                  hipFuncAttributeMaxDynamicSharedMemorySize, 131072);
        const float* xa = x;
        const unsigned short *a0 = WH0, *a1 = WL0, *a2 = WH1, *a3 = WL1,
                             *a4 = WH2, *a5 = WL2, *a6 = WH3, *a7 = WL3;
        const float* br = biasR;
        unsigned short *bh = bndH, *bl = bndL;
        void* args[] = { (void*)&xa, (void*)&a0, (void*)&a1, (void*)&a2, (void*)&a3,
                         (void*)&a4, (void*)&a5, (void*)&a6, (void*)&a7,
                         (void*)&br, (void*)&bh, (void*)&bl };
        hipError_t rc = hipLaunchCooperativeKernel((void*)lstm_pipe, dim3(256), dim3(1024),
                                                   args, 131072, stream);
        if (rc != hipSuccess) {
            sentinel_fill<<<1, 256, 0, stream>>>(out, -22222.0f);
            return;
        }
    }

    mlp_head<<<256, 128, 0, stream>>>(bndH, bndL, W1, b1, W2, b2, W3, b3, out);
}

// Round 15
// 13401.318 us; speedup vs baseline: 5.1824x; 1.7088x over previous
//
#include <hip/hip_runtime.h>
#include <hip/hip_bf16.h>
#include <hip/hip_cooperative_groups.h>
#include <cstdint>

static constexpr int B_ = 256;
static constexpr int T_ = 512;
static constexpr int I_ = 64;
static constexpr int H_ = 512;
static constexpr int G_ = 2048;            // gate cols, col = 4*j + g
static constexpr int L_ = 4;
static constexpr int NSTEP = T_ + L_ - 1;  // 515

typedef __attribute__((ext_vector_type(8))) short short8;   // 8 bf16
typedef __attribute__((ext_vector_type(4))) float f32x4;
typedef __attribute__((ext_vector_type(4))) unsigned int u32x4;

__device__ __forceinline__ float bfu2f(unsigned short u) {
    return __uint_as_float(((unsigned int)u) << 16);
}
__device__ __forceinline__ unsigned short f2bfu(float v) {
    __hip_bfloat16 h = __float2bfloat16(v);   // RNE
    return *(unsigned short*)&h;
}

// ---------- weight prep: per-(layer, 32-col slice) B-frag layout, split hi/lo ----------
__global__ void prep_wtfrag(const float* __restrict__ Whh_l,
                            const float* __restrict__ Wih_l,
                            int Kin, int NKB,
                            unsigned short* __restrict__ WH,
                            unsigned short* __restrict__ WL)
{
    const size_t total = (size_t)(H_ + Kin) * G_;
    const size_t Sl = (size_t)2 * NKB * 512;
    for (size_t idx = (size_t)blockIdx.x * blockDim.x + threadIdx.x; idx < total;
         idx += (size_t)gridDim.x * blockDim.x) {
        const int k = (int)(idx >> 11);
        const int n = (int)(idx & 2047);
        const int j = n >> 2, g = n & 3;
        const int r = g * H_ + j;
        const float w = (k < H_) ? Whh_l[(size_t)r * H_ + k]
                                 : Wih_l[(size_t)r * Kin + (k - H_)];
        const int ns = n >> 5, ntl = (n >> 4) & 1, n16 = n & 15;
        const int kb = k >> 5, bq = (k >> 3) & 3, kk = k & 7;
        const size_t off = (size_t)ns * Sl
                         + ((size_t)(ntl * NKB + kb) * 64 + (n16 + (bq << 4))) * 8 + kk;
        const unsigned short hi = f2bfu(w);
        WH[off] = hi;
        WL[off] = f2bfu(w - bfu2f(hi));
    }
}

__global__ void prep_bias(const float* __restrict__ bih, const float* __restrict__ bhh,
                          float* __restrict__ biasR)
{
    const int idx = blockIdx.x * blockDim.x + threadIdx.x;
    if (idx < L_ * G_) {
        const int l   = idx >> 11;
        const int col = idx & 2047;
        const int j = col >> 2, g = col & 3;
        const int r = l * G_ + g * H_ + j;
        biasR[idx] = bih[r] + bhh[r];
    }
}

__global__ void sentinel_fill(float* out, float v) { out[threadIdx.x] = v; }

// ---------- pipelined 4-layer LSTM: LDS weights + LEAN agent-scope barrier ----------
// Structure = round-14 (22.9 ms, bit-exact).  Change: cg::grid.sync() (system-scope
// fences + heavy protocol, ~35 us/step) -> hand-rolled monotonic barrier:
//   __syncthreads (stores drained to L2 by compiler's vmcnt(0))
//   t0: fence(RELEASE, agent)  = buffer_wbl2, ~2KB dirty/block
//       atomicAdd on XCD-sharded counter (8 shards, 256B apart)  [r13 lesson: contention]
//       spin on sum(shards) >= 256*(s+1)   (monotonic -> deadlock-free; bounded guard)
//       fence(ACQUIRE, agent)  = buffer_inv (tag-only, no L3 flush)
//   __syncthreads
// Cooperative launch kept ONLY for co-residency guarantee.
__global__ __launch_bounds__(1024, 4)
void lstm_pipe(const float* __restrict__ x,
               const unsigned short* __restrict__ WH0, const unsigned short* __restrict__ WL0,
               const unsigned short* __restrict__ WH1, const unsigned short* __restrict__ WL1,
               const unsigned short* __restrict__ WH2, const unsigned short* __restrict__ WL2,
               const unsigned short* __restrict__ WH3, const unsigned short* __restrict__ WL3,
               const float* __restrict__ biasR,
               unsigned short* __restrict__ bndH, unsigned short* __restrict__ bndL,
               int* __restrict__ bar)
{
    extern __shared__ unsigned short wgt[];   // [split2][ntl2][kb32][lane64][kk8] = 131072 B

    const int tid = threadIdx.x;
    const int blk = blockIdx.x;
    const int l   = blk >> 6;
    const int cs  = blk & 63;
    const int lane = tid & 63;
    const int wv   = tid >> 6;           // 0..15
    const int bcw  = wv >> 1;            // batch chunk (32 rows)
    const int mtw  = wv & 1;

    const unsigned short* __restrict__ WHl = (l == 0) ? WH0 : (l == 1) ? WH1 : (l == 2) ? WH2 : WH3;
    const unsigned short* __restrict__ WLl = (l == 0) ? WL0 : (l == 1) ? WL1 : (l == 2) ? WL2 : WL3;
    const int NKB = (l == 0) ? 18 : 32;

    // ---- one-time: copy this block's weight slice into LDS ----
    {
        const size_t gb = (size_t)cs * (2 * NKB * 512);
        const int chunks = 2 * NKB * 64;
        for (int c = tid; c < chunks; c += 1024) {
            const int ntl = c / (NKB * 64);
            const int r   = c - ntl * (NKB * 64);
            const int kb  = r >> 6, ln = r & 63;
            const size_t so = gb + ((size_t)(ntl * NKB + kb) * 64 + ln) * 8;
            const int dof = ((ntl * 32 + kb) * 64 + ln) * 8;
            *(u32x4*)&wgt[dof]         = *(const u32x4*)(WHl + so);
            *(u32x4*)&wgt[32768 + dof] = *(const u32x4*)(WLl + so);
        }
    }
    __syncthreads();

    // epilogue mapping (after 4x4 shfl transpose)
    const int dl  = lane & 3;
    const int u0  = (lane & 15) >> 2;
    const int row = bcw * 32 + mtw * 16 + ((lane >> 4) << 2) + dl;
    const int j0  = cs * 8 + u0;
    const int j1  = j0 + 4;
    const float4 bias0 = *(const float4*)(biasR + l * G_ + (j0 << 2));
    const float4 bias1 = *(const float4*)(biasR + l * G_ + (j1 << 2));
    const int bc2 = row >> 5, mt2 = (row >> 4) & 1, m16r = row & 15;
    auto h_eo = [&](int j) -> size_t {
        return (size_t)(j >> 5) * 1024 + (size_t)mt2 * 512
             + (size_t)(m16r + (((j >> 3) & 3) << 4)) * 8 + (j & 7);
    };
    const size_t eo0 = h_eo(j0), eo1 = h_eo(j1);

    auto xpose = [&](f32x4& v) {
        float t0 = __shfl_xor(v[1], 1);
        float t1 = __shfl_xor(v[0], 1);
        float t2 = __shfl_xor(v[3], 1);
        float t3 = __shfl_xor(v[2], 1);
        if (dl & 1) { v[0] = t0; v[2] = t2; } else { v[1] = t1; v[3] = t3; }
        float s0 = __shfl_xor(v[2], 2);
        float s1 = __shfl_xor(v[3], 2);
        float s2 = __shfl_xor(v[0], 2);
        float s3 = __shfl_xor(v[1], 2);
        if (dl & 2) { v[0] = s0; v[1] = s1; } else { v[2] = s2; v[3] = s3; }
    };

    float c0 = 0.f, c1 = 0.f;

    for (int s = 0; s < NSTEP; ++s) {
        const int t = s - l;
        if (0 <= t && t < T_) {
            const int pr = (s + 1) & 1;
            const int pw = s & 1;
            const size_t ebOwn = ((size_t)(l * 2 + pr) * 8 + bcw) * 16384
                               + (size_t)mtw * 512 + (size_t)lane * 8;

            f32x4 C0 = {0.f, 0.f, 0.f, 0.f};
            f32x4 C1 = {0.f, 0.f, 0.f, 0.f};

            if (l > 0) {
                const size_t ebIn = ((size_t)((l - 1) * 2 + pr) * 8 + bcw) * 16384
                                  + (size_t)mtw * 512 + (size_t)lane * 8;
                const unsigned short* aHo = bndH + ebOwn;
                const unsigned short* aLo = bndL + ebOwn;
                const unsigned short* aHi = bndH + ebIn;
                const unsigned short* aLi = bndL + ebIn;
#pragma unroll 4
                for (int kbl = 0; kbl < 16; ++kbl) {
                    const short8 a0H = *(const short8*)(aHo + kbl * 1024);
                    const short8 a0L = *(const short8*)(aLo + kbl * 1024);
                    const short8 a1H = *(const short8*)(aHi + kbl * 1024);
                    const short8 a1L = *(const short8*)(aLi + kbl * 1024);
                    const int wo0 = kbl * 512 + lane * 8;
                    const int wo1 = (16 + kbl) * 512 + lane * 8;
                    const short8 wH0o = *(const short8*)&wgt[wo0];
                    const short8 wL0o = *(const short8*)&wgt[32768 + wo0];
                    const short8 wH1o = *(const short8*)&wgt[16384 + wo0];
                    const short8 wL1o = *(const short8*)&wgt[49152 + wo0];
                    const short8 wH0i = *(const short8*)&wgt[wo1];
                    const short8 wL0i = *(const short8*)&wgt[32768 + wo1];
                    const short8 wH1i = *(const short8*)&wgt[16384 + wo1];
                    const short8 wL1i = *(const short8*)&wgt[49152 + wo1];
                    C0 = __builtin_amdgcn_mfma_f32_16x16x32_bf16(a0H, wH0o, C0, 0, 0, 0);
                    C0 = __builtin_amdgcn_mfma_f32_16x16x32_bf16(a0L, wH0o, C0, 0, 0, 0);
                    C0 = __builtin_amdgcn_mfma_f32_16x16x32_bf16(a0H, wL0o, C0, 0, 0, 0);
                    C1 = __builtin_amdgcn_mfma_f32_16x16x32_bf16(a0H, wH1o, C1, 0, 0, 0);
                    C1 = __builtin_amdgcn_mfma_f32_16x16x32_bf16(a0L, wH1o, C1, 0, 0, 0);
                    C1 = __builtin_amdgcn_mfma_f32_16x16x32_bf16(a0H, wL1o, C1, 0, 0, 0);
                    C0 = __builtin_amdgcn_mfma_f32_16x16x32_bf16(a1H, wH0i, C0, 0, 0, 0);
                    C0 = __builtin_amdgcn_mfma_f32_16x16x32_bf16(a1L, wH0i, C0, 0, 0, 0);
                    C0 = __builtin_amdgcn_mfma_f32_16x16x32_bf16(a1H, wL0i, C0, 0, 0, 0);
                    C1 = __builtin_amdgcn_mfma_f32_16x16x32_bf16(a1H, wH1i, C1, 0, 0, 0);
                    C1 = __builtin_amdgcn_mfma_f32_16x16x32_bf16(a1L, wH1i, C1, 0, 0, 0);
                    C1 = __builtin_amdgcn_mfma_f32_16x16x32_bf16(a1H, wL1i, C1, 0, 0, 0);
                }
            } else {
                const int rowa = bcw * 32 + mtw * 16 + (lane & 15);
                const float* xb = x + ((size_t)rowa * T_ + t) * I_ + ((lane >> 4) << 3);
                float4 xf0 = *(const float4*)(xb);
                float4 xf1 = *(const float4*)(xb + 4);
                float4 xf2 = *(const float4*)(xb + 32);
                float4 xf3 = *(const float4*)(xb + 36);

                const unsigned short* aHo = bndH + ebOwn;
                const unsigned short* aLo = bndL + ebOwn;
#pragma unroll 4
                for (int kbl = 0; kbl < 16; ++kbl) {
                    const short8 a0H = *(const short8*)(aHo + kbl * 1024);
                    const short8 a0L = *(const short8*)(aLo + kbl * 1024);
                    const int wo0 = kbl * 512 + lane * 8;
                    const short8 wH0o = *(const short8*)&wgt[wo0];
                    const short8 wL0o = *(const short8*)&wgt[32768 + wo0];
                    const short8 wH1o = *(const short8*)&wgt[16384 + wo0];
                    const short8 wL1o = *(const short8*)&wgt[49152 + wo0];
                    C0 = __builtin_amdgcn_mfma_f32_16x16x32_bf16(a0H, wH0o, C0, 0, 0, 0);
                    C0 = __builtin_amdgcn_mfma_f32_16x16x32_bf16(a0L, wH0o, C0, 0, 0, 0);
                    C0 = __builtin_amdgcn_mfma_f32_16x16x32_bf16(a0H, wL0o, C0, 0, 0, 0);
                    C1 = __builtin_amdgcn_mfma_f32_16x16x32_bf16(a0H, wH1o, C1, 0, 0, 0);
                    C1 = __builtin_amdgcn_mfma_f32_16x16x32_bf16(a0L, wH1o, C1, 0, 0, 0);
                    C1 = __builtin_amdgcn_mfma_f32_16x16x32_bf16(a0H, wL1o, C1, 0, 0, 0);
                }
                float xv[16];
                *(float4*)&xv[0]  = xf0;  *(float4*)&xv[4]  = xf1;
                *(float4*)&xv[8]  = xf2;  *(float4*)&xv[12] = xf3;
#pragma unroll
                for (int kbl = 0; kbl < 2; ++kbl) {
                    short8 aH, aL;
#pragma unroll
                    for (int e = 0; e < 8; ++e) {
                        const float v = xv[kbl * 8 + e];
                        const unsigned short hi = f2bfu(v);
                        aH[e] = (short)hi;
                        aL[e] = (short)f2bfu(v - bfu2f(hi));
                    }
                    const int wo = (16 + kbl) * 512 + lane * 8;
                    const short8 wH0 = *(const short8*)&wgt[wo];
                    const short8 wL0 = *(const short8*)&wgt[32768 + wo];
                    const short8 wH1 = *(const short8*)&wgt[16384 + wo];
                    const short8 wL1 = *(const short8*)&wgt[49152 + wo];
                    C0 = __builtin_amdgcn_mfma_f32_16x16x32_bf16(aH, wH0, C0, 0, 0, 0);
                    C0 = __builtin_amdgcn_mfma_f32_16x16x32_bf16(aL, wH0, C0, 0, 0, 0);
                    C0 = __builtin_amdgcn_mfma_f32_16x16x32_bf16(aH, wL0, C0, 0, 0, 0);
                    C1 = __builtin_amdgcn_mfma_f32_16x16x32_bf16(aH, wH1, C1, 0, 0, 0);
                    C1 = __builtin_amdgcn_mfma_f32_16x16x32_bf16(aL, wH1, C1, 0, 0, 0);
                    C1 = __builtin_amdgcn_mfma_f32_16x16x32_bf16(aH, wL1, C1, 0, 0, 0);
                }
            }

            xpose(C0);
            xpose(C1);

            const size_t wb = ((size_t)(l * 2 + pw) * 8 + bc2) * 16384;
            {
                const float gi = C0[0] + bias0.x;
                const float gf = C0[1] + bias0.y;
                const float gg = C0[2] + bias0.z;
                const float go = C0[3] + bias0.w;
                const float iv = 1.f / (1.f + expf(-gi));
                const float fv = 1.f / (1.f + expf(-gf));
                const float gv = tanhf(gg);
                const float ov = 1.f / (1.f + expf(-go));
                c0 = fv * c0 + iv * gv;
                const float hv = ov * tanhf(c0);
                const unsigned short hi = f2bfu(hv);
                bndH[wb + eo0] = hi;
                bndL[wb + eo0] = f2bfu(hv - bfu2f(hi));
            }
            {
                const float gi = C1[0] + bias1.x;
                const float gf = C1[1] + bias1.y;
                const float gg = C1[2] + bias1.z;
                const float go = C1[3] + bias1.w;
                const float iv = 1.f / (1.f + expf(-gi));
                const float fv = 1.f / (1.f + expf(-gf));
                const float gv = tanhf(gg);
                const float ov = 1.f / (1.f + expf(-go));
                c1 = fv * c1 + iv * gv;
                const float hv = ov * tanhf(c1);
                const unsigned short hi = f2bfu(hv);
                bndH[wb + eo1] = hi;
                bndL[wb + eo1] = f2bfu(hv - bfu2f(hi));
            }
        }

        // ---- lean agent-scope barrier (replaces cg::grid.sync) ----
        if (s != NSTEP - 1) {
            __syncthreads();   // all waves' stores drained to L2 (compiler vmcnt(0))
            if (tid == 0) {
                __builtin_amdgcn_fence(__ATOMIC_RELEASE, "agent");   // wbl2 (tiny dirty set)
                __hip_atomic_fetch_add(bar + ((blk & 7) << 6), 1,
                                       __ATOMIC_RELAXED, __HIP_MEMORY_SCOPE_AGENT);
                const int target = 256 * (s + 1);
                int guard = 0;
                for (;;) {
                    int sum = 0;
#pragma unroll
                    for (int i = 0; i < 8; ++i)
                        sum += __hip_atomic_load(bar + (i << 6), __ATOMIC_RELAXED,
                                                 __HIP_MEMORY_SCOPE_AGENT);
                    if (sum >= target) break;
                    if (++guard > (1 << 20)) break;   // escape hatch: wrong-answer, not hang
                    __builtin_amdgcn_s_sleep(1);
                }
                __builtin_amdgcn_fence(__ATOMIC_ACQUIRE, "agent");   // buffer_inv (tag-only)
            }
            __syncthreads();
        }
    }
}

// ---------- MLP head: reads h_3[T-1] (parity 0) from bnd frag layout ----------
__global__ __launch_bounds__(128)
void mlp_head(const unsigned short* __restrict__ bndH, const unsigned short* __restrict__ bndL,
              const float* __restrict__ W1, const float* __restrict__ b1,
              const float* __restrict__ W2, const float* __restrict__ b2,
              const float* __restrict__ W3, const float* __restrict__ b3,
              float* __restrict__ out)
{
    __shared__ float hl[H_];
    __shared__ float a1[128];
    __shared__ float a2[64];
    const int b = blockIdx.x, tid = threadIdx.x;
    {
        const int bc = b >> 5, m = b & 31;
        const int mtt = m >> 4, m16 = m & 15;
        const size_t base = ((size_t)48 + bc) * 16384;   // (3*2+0)*8 + bc
        const int k0 = tid << 2;
        const int kb = k0 >> 5, bq = (k0 >> 3) & 3, kk0 = k0 & 7;
        const size_t eo = base + ((size_t)((kb << 1) + mtt) * 64 + (m16 + (bq << 4))) * 8 + kk0;
        const ushort4 vh = *(const ushort4*)(bndH + eo);
        const ushort4 vl = *(const ushort4*)(bndL + eo);
        hl[k0 + 0] = bfu2f(vh.x) + bfu2f(vl.x);
        hl[k0 + 1] = bfu2f(vh.y) + bfu2f(vl.y);
        hl[k0 + 2] = bfu2f(vh.z) + bfu2f(vl.z);
        hl[k0 + 3] = bfu2f(vh.w) + bfu2f(vl.w);
    }
    __syncthreads();
    {
        float s = b1[tid];
        const float* wr = W1 + (size_t)tid * H_;
        for (int k = 0; k < H_; ++k) s = fmaf(wr[k], hl[k], s);
        a1[tid] = fmaxf(s, 0.f);
    }
    __syncthreads();
    if (tid < 64) {
        float s = b2[tid];
        const float* wr = W2 + (tid << 7);
        for (int k = 0; k < 128; ++k) s = fmaf(wr[k], a1[k], s);
        a2[tid] = fmaxf(s, 0.f);
    }
    __syncthreads();
    if (tid < 64) {
        float v = W3[tid] * a2[tid];
        for (int off = 32; off; off >>= 1) v += __shfl_down(v, off);
        if (tid == 0) out[b] = v + b3[0];
    }
}

extern "C" void kernel_launch(void* const* d_in, const int* in_sizes, int n_in,
                              void* d_out, int out_size, void* d_ws, size_t ws_size,
                              hipStream_t stream)
{
    const float* x    = (const float*)d_in[0];
    const float* Wih0 = (const float*)d_in[1];
    const float* WihR = (const float*)d_in[2];
    const float* Whh  = (const float*)d_in[3];
    const float* bih  = (const float*)d_in[4];
    const float* bhh  = (const float*)d_in[5];
    const float* W1   = (const float*)d_in[6];
    const float* b1   = (const float*)d_in[7];
    const float* W2   = (const float*)d_in[8];
    const float* b2   = (const float*)d_in[9];
    const float* W3   = (const float*)d_in[10];
    const float* b3   = (const float*)d_in[11];
    float* out = (float*)d_out;

    const size_t W0e = (size_t)(H_ + I_) * G_;       // 1,179,648 elems (NKB=18)
    const size_t W1e = (size_t)(2 * H_) * G_;        // 2,097,152 elems (NKB=32)
    const size_t biasE = (size_t)L_ * G_;            // 8192
    const size_t bndE  = (size_t)64 * 16384;         // 1,048,576 elems per split
    const size_t barE  = 8 * 64;                     // 8 shards, 256B apart

    auto align256 = [](size_t v) { return (v + 255) & ~(size_t)255; };
    const size_t need = 2 * align256(W0e * 2) + 6 * align256(W1e * 2)
                      + align256(biasE * 4) + align256(barE * sizeof(int))
                      + 2 * align256(bndE * 2);

    char* ws = (char*)d_ws;
    size_t off = 0;
    auto alloc = [&](size_t bytes) -> void* {
        void* p = ws + off;
        off = align256(off + bytes);
        return p;
    };

    if (ws_size < need) {
        sentinel_fill<<<1, 256, 0, stream>>>(out, -11111.0f);
        return;
    }

    unsigned short* WH0 = (unsigned short*)alloc(W0e * 2);
    unsigned short* WL0 = (unsigned short*)alloc(W0e * 2);
    unsigned short* WH1 = (unsigned short*)alloc(W1e * 2);
    unsigned short* WL1 = (unsigned short*)alloc(W1e * 2);
    unsigned short* WH2 = (unsigned short*)alloc(W1e * 2);
    unsigned short* WL2 = (unsigned short*)alloc(W1e * 2);
    unsigned short* WH3 = (unsigned short*)alloc(W1e * 2);
    unsigned short* WL3 = (unsigned short*)alloc(W1e * 2);
    float* biasR = (float*)alloc(biasE * 4);
    int*   bar   = (int*)alloc(barE * sizeof(int));
    unsigned short* bndH = (unsigned short*)alloc(bndE * 2);
    unsigned short* bndL = (unsigned short*)alloc(bndE * 2);

    const size_t WL_ = (size_t)G_ * H_;
    prep_wtfrag<<<1024, 256, 0, stream>>>(Whh + 0 * WL_, Wih0,           I_, 18, WH0, WL0);
    prep_wtfrag<<<1024, 256, 0, stream>>>(Whh + 1 * WL_, WihR + 0 * WL_, H_, 32, WH1, WL1);
    prep_wtfrag<<<1024, 256, 0, stream>>>(Whh + 2 * WL_, WihR + 1 * WL_, H_, 32, WH2, WL2);
    prep_wtfrag<<<1024, 256, 0, stream>>>(Whh + 3 * WL_, WihR + 2 * WL_, H_, 32, WH3, WL3);
    prep_bias<<<(L_ * G_ + 255) / 256, 256, 0, stream>>>(bih, bhh, biasR);
    (void)hipMemsetAsync(bar, 0, barE * sizeof(int), stream);
    (void)hipMemsetAsync(bndH, 0, bndE * 2, stream);
    (void)hipMemsetAsync(bndL, 0, bndE * 2, stream);

    {
        (void)hipFuncSetAttribute((const void*)lstm_pipe,
                                  hipFuncAttributeMaxDynamicSharedMemorySize, 131072);
        const float* xa = x;
        const unsigned short *a0 = WH0, *a1 = WL0, *a2 = WH1, *a3 = WL1,
                             *a4 = WH2, *a5 = WL2, *a6 = WH3, *a7 = WL3;
        const float* br = biasR;
        unsigned short *bh = bndH, *bl = bndL;
        int* bp = bar;
        void* args[] = { (void*)&xa, (void*)&a0, (void*)&a1, (void*)&a2, (void*)&a3,
                         (void*)&a4, (void*)&a5, (void*)&a6, (void*)&a7,
                         (void*)&br, (void*)&bh, (void*)&bl, (void*)&bp };
        hipError_t rc = hipLaunchCooperativeKernel((void*)lstm_pipe, dim3(256), dim3(1024),
                                                   args, 131072, stream);
        if (rc != hipSuccess) {
            sentinel_fill<<<1, 256, 0, stream>>>(out, -22222.0f);
            return;
        }
    }

    mlp_head<<<256, 128, 0, stream>>>(bndH, bndL, W1, b1, W2, b2, W3, b3, out);
}

// Round 16
// 9267.732 us; speedup vs baseline: 7.4939x; 1.4460x over previous
//
#include <hip/hip_runtime.h>
#include <hip/hip_bf16.h>
#include <hip/hip_cooperative_groups.h>
#include <cstdint>

static constexpr int B_ = 256;
static constexpr int T_ = 512;
static constexpr int I_ = 64;
static constexpr int H_ = 512;
static constexpr int G_ = 2048;            // gate cols, col = 4*j + g
static constexpr int L_ = 4;
static constexpr int NSTEP = T_ + L_ - 1;  // 515

typedef __attribute__((ext_vector_type(8))) short short8;   // 8 bf16
typedef __attribute__((ext_vector_type(4))) float f32x4;
typedef __attribute__((ext_vector_type(4))) unsigned int u32x4;

__device__ __forceinline__ float bfu2f(unsigned short u) {
    return __uint_as_float(((unsigned int)u) << 16);
}
__device__ __forceinline__ unsigned short f2bfu(float v) {
    __hip_bfloat16 h = __float2bfloat16(v);   // RNE
    return *(unsigned short*)&h;
}
// fast sigmoid/tanh: v_exp + v_rcp (~1e-7 rel err; output threshold is 5e-4)
__device__ __forceinline__ float fsigm(float x) {
    return __builtin_amdgcn_rcpf(1.f + __expf(-x));   // x->+inf: rcp(1)=1; x->-inf: rcp(inf)=0
}
__device__ __forceinline__ float ftanh(float x) {
    const float xc = fminf(fmaxf(x, -15.f), 15.f);    // clamp: e^30 finite
    const float e2 = __expf(2.f * xc);
    return (e2 - 1.f) * __builtin_amdgcn_rcpf(e2 + 1.f);
}

// ---------- weight prep: per-(layer, 32-col slice) B-frag layout, split hi/lo ----------
__global__ void prep_wtfrag(const float* __restrict__ Whh_l,
                            const float* __restrict__ Wih_l,
                            int Kin, int NKB,
                            unsigned short* __restrict__ WH,
                            unsigned short* __restrict__ WL)
{
    const size_t total = (size_t)(H_ + Kin) * G_;
    const size_t Sl = (size_t)2 * NKB * 512;
    for (size_t idx = (size_t)blockIdx.x * blockDim.x + threadIdx.x; idx < total;
         idx += (size_t)gridDim.x * blockDim.x) {
        const int k = (int)(idx >> 11);
        const int n = (int)(idx & 2047);
        const int j = n >> 2, g = n & 3;
        const int r = g * H_ + j;
        const float w = (k < H_) ? Whh_l[(size_t)r * H_ + k]
                                 : Wih_l[(size_t)r * Kin + (k - H_)];
        const int ns = n >> 5, ntl = (n >> 4) & 1, n16 = n & 15;
        const int kb = k >> 5, bq = (k >> 3) & 3, kk = k & 7;
        const size_t off = (size_t)ns * Sl
                         + ((size_t)(ntl * NKB + kb) * 64 + (n16 + (bq << 4))) * 8 + kk;
        const unsigned short hi = f2bfu(w);
        WH[off] = hi;
        WL[off] = f2bfu(w - bfu2f(hi));
    }
}

__global__ void prep_bias(const float* __restrict__ bih, const float* __restrict__ bhh,
                          float* __restrict__ biasR)
{
    const int idx = blockIdx.x * blockDim.x + threadIdx.x;
    if (idx < L_ * G_) {
        const int l   = idx >> 11;
        const int col = idx & 2047;
        const int j = col >> 2, g = col & 3;
        const int r = l * G_ + g * H_ + j;
        biasR[idx] = bih[r] + bhh[r];
    }
}

__global__ void sentinel_fill(float* out, float v) { out[threadIdx.x] = v; }

// ---------- pipelined 4-layer LSTM: LDS weights + write-through h + zero-wbl2 barrier ----------
// Structure = round-15 (13.4 ms).  Changes:
//  (1) h(t) stores: LDS-bounced into 32 contiguous 256B chunks, then written via
//      agent-scope RELAXED ATOMIC u64 stores (sc1 write-through -> lands in L3, no dirty L2).
//  (2) barrier: __syncthreads (vmcnt drains write-through stores TO L3) -> tid0 relaxed
//      shard-add -> relaxed spin -> fence(ACQUIRE, agent) (buffer_inv only; NO wbl2 anywhere)
//      -> __syncthreads.  Release fence deleted: nothing dirty to flush.
//  (3) fast sigmoid/tanh via v_exp/v_rcp.
__global__ __launch_bounds__(1024, 4)
void lstm_pipe(const float* __restrict__ x,
               const unsigned short* __restrict__ WH0, const unsigned short* __restrict__ WL0,
               const unsigned short* __restrict__ WH1, const unsigned short* __restrict__ WL1,
               const unsigned short* __restrict__ WH2, const unsigned short* __restrict__ WL2,
               const unsigned short* __restrict__ WH3, const unsigned short* __restrict__ WL3,
               const float* __restrict__ biasR,
               unsigned short* __restrict__ bndH, unsigned short* __restrict__ bndL,
               int* __restrict__ bar)
{
    extern __shared__ unsigned short wgt[];   // weights 131072 B + hout 8192 B = 139264 B

    const int tid = threadIdx.x;
    const int blk = blockIdx.x;
    const int l   = blk >> 6;
    const int cs  = blk & 63;
    const int lane = tid & 63;
    const int wv   = tid >> 6;           // 0..15
    const int bcw  = wv >> 1;            // batch chunk (32 rows)
    const int mtw  = wv & 1;

    unsigned short* __restrict__ hout = wgt + 65536;   // [split2][bc8][mt2][128] ushort = 8 KB

    const unsigned short* __restrict__ WHl = (l == 0) ? WH0 : (l == 1) ? WH1 : (l == 2) ? WH2 : WH3;
    const unsigned short* __restrict__ WLl = (l == 0) ? WL0 : (l == 1) ? WL1 : (l == 2) ? WL2 : WL3;
    const int NKB = (l == 0) ? 18 : 32;

    // ---- one-time: copy this block's weight slice into LDS ----
    {
        const size_t gb = (size_t)cs * (2 * NKB * 512);
        const int chunks = 2 * NKB * 64;
        for (int c = tid; c < chunks; c += 1024) {
            const int ntl = c / (NKB * 64);
            const int r   = c - ntl * (NKB * 64);
            const int kb  = r >> 6, ln = r & 63;
            const size_t so = gb + ((size_t)(ntl * NKB + kb) * 64 + ln) * 8;
            const int dof = ((ntl * 32 + kb) * 64 + ln) * 8;
            *(u32x4*)&wgt[dof]         = *(const u32x4*)(WHl + so);
            *(u32x4*)&wgt[32768 + dof] = *(const u32x4*)(WLl + so);
        }
    }
    __syncthreads();

    // epilogue mapping (after 4x4 shfl transpose): thread owns (row, j0) and (row, j1)
    const int dl  = lane & 3;
    const int u0  = (lane & 15) >> 2;
    const int row = bcw * 32 + mtw * 16 + ((lane >> 4) << 2) + dl;
    const int j0  = cs * 8 + u0;                 // j&7 = u0 ; j1&7 = u0+4
    const int j1  = j0 + 4;
    const float4 bias0 = *(const float4*)(biasR + l * G_ + (j0 << 2));
    const float4 bias1 = *(const float4*)(biasR + l * G_ + (j1 << 2));
    const int bc2 = row >> 5, mt2 = (row >> 4) & 1, m16r = row & 15;
    // LDS hout index: ((split*8+bc)*2+mt)*128 + m16r*8 + kk
    const int lbase = (((bc2 << 1) + mt2) << 7) + (m16r << 3);
    // store-pass constants: chunk c = tid>>5 -> split=c>>4, bc=(c>>1)&7, mt=c&1; pos = tid&31
    const int kbC = cs >> 2, bqC = cs & 3;
    const int spC = tid >> 10;                   // always 0; decoded below from c
    (void)spC;

    auto xpose = [&](f32x4& v) {
        float t0 = __shfl_xor(v[1], 1);
        float t1 = __shfl_xor(v[0], 1);
        float t2 = __shfl_xor(v[3], 1);
        float t3 = __shfl_xor(v[2], 1);
        if (dl & 1) { v[0] = t0; v[2] = t2; } else { v[1] = t1; v[3] = t3; }
        float s0 = __shfl_xor(v[2], 2);
        float s1 = __shfl_xor(v[3], 2);
        float s2 = __shfl_xor(v[0], 2);
        float s3 = __shfl_xor(v[1], 2);
        if (dl & 2) { v[0] = s0; v[1] = s1; } else { v[2] = s2; v[3] = s3; }
    };

    float c0 = 0.f, c1 = 0.f;

    for (int s = 0; s < NSTEP; ++s) {
        const int t = s - l;
        if (0 <= t && t < T_) {
            const int pr = (s + 1) & 1;
            const int pw = s & 1;
            const size_t ebOwn = ((size_t)(l * 2 + pr) * 8 + bcw) * 16384
                               + (size_t)mtw * 512 + (size_t)lane * 8;

            f32x4 C0 = {0.f, 0.f, 0.f, 0.f};
            f32x4 C1 = {0.f, 0.f, 0.f, 0.f};

            if (l > 0) {
                const size_t ebIn = ((size_t)((l - 1) * 2 + pr) * 8 + bcw) * 16384
                                  + (size_t)mtw * 512 + (size_t)lane * 8;
                const unsigned short* aHo = bndH + ebOwn;
                const unsigned short* aLo = bndL + ebOwn;
                const unsigned short* aHi = bndH + ebIn;
                const unsigned short* aLi = bndL + ebIn;
#pragma unroll 4
                for (int kbl = 0; kbl < 16; ++kbl) {
                    const short8 a0H = *(const short8*)(aHo + kbl * 1024);
                    const short8 a0L = *(const short8*)(aLo + kbl * 1024);
                    const short8 a1H = *(const short8*)(aHi + kbl * 1024);
                    const short8 a1L = *(const short8*)(aLi + kbl * 1024);
                    const int wo0 = kbl * 512 + lane * 8;
                    const int wo1 = (16 + kbl) * 512 + lane * 8;
                    const short8 wH0o = *(const short8*)&wgt[wo0];
                    const short8 wL0o = *(const short8*)&wgt[32768 + wo0];
                    const short8 wH1o = *(const short8*)&wgt[16384 + wo0];
                    const short8 wL1o = *(const short8*)&wgt[49152 + wo0];
                    const short8 wH0i = *(const short8*)&wgt[wo1];
                    const short8 wL0i = *(const short8*)&wgt[32768 + wo1];
                    const short8 wH1i = *(const short8*)&wgt[16384 + wo1];
                    const short8 wL1i = *(const short8*)&wgt[49152 + wo1];
                    C0 = __builtin_amdgcn_mfma_f32_16x16x32_bf16(a0H, wH0o, C0, 0, 0, 0);
                    C0 = __builtin_amdgcn_mfma_f32_16x16x32_bf16(a0L, wH0o, C0, 0, 0, 0);
                    C0 = __builtin_amdgcn_mfma_f32_16x16x32_bf16(a0H, wL0o, C0, 0, 0, 0);
                    C1 = __builtin_amdgcn_mfma_f32_16x16x32_bf16(a0H, wH1o, C1, 0, 0, 0);
                    C1 = __builtin_amdgcn_mfma_f32_16x16x32_bf16(a0L, wH1o, C1, 0, 0, 0);
                    C1 = __builtin_amdgcn_mfma_f32_16x16x32_bf16(a0H, wL1o, C1, 0, 0, 0);
                    C0 = __builtin_amdgcn_mfma_f32_16x16x32_bf16(a1H, wH0i, C0, 0, 0, 0);
                    C0 = __builtin_amdgcn_mfma_f32_16x16x32_bf16(a1L, wH0i, C0, 0, 0, 0);
                    C0 = __builtin_amdgcn_mfma_f32_16x16x32_bf16(a1H, wL0i, C0, 0, 0, 0);
                    C1 = __builtin_amdgcn_mfma_f32_16x16x32_bf16(a1H, wH1i, C1, 0, 0, 0);
                    C1 = __builtin_amdgcn_mfma_f32_16x16x32_bf16(a1L, wH1i, C1, 0, 0, 0);
                    C1 = __builtin_amdgcn_mfma_f32_16x16x32_bf16(a1H, wL1i, C1, 0, 0, 0);
                }
            } else {
                const int rowa = bcw * 32 + mtw * 16 + (lane & 15);
                const float* xb = x + ((size_t)rowa * T_ + t) * I_ + ((lane >> 4) << 3);
                float4 xf0 = *(const float4*)(xb);
                float4 xf1 = *(const float4*)(xb + 4);
                float4 xf2 = *(const float4*)(xb + 32);
                float4 xf3 = *(const float4*)(xb + 36);

                const unsigned short* aHo = bndH + ebOwn;
                const unsigned short* aLo = bndL + ebOwn;
#pragma unroll 4
                for (int kbl = 0; kbl < 16; ++kbl) {
                    const short8 a0H = *(const short8*)(aHo + kbl * 1024);
                    const short8 a0L = *(const short8*)(aLo + kbl * 1024);
                    const int wo0 = kbl * 512 + lane * 8;
                    const short8 wH0o = *(const short8*)&wgt[wo0];
                    const short8 wL0o = *(const short8*)&wgt[32768 + wo0];
                    const short8 wH1o = *(const short8*)&wgt[16384 + wo0];
                    const short8 wL1o = *(const short8*)&wgt[49152 + wo0];
                    C0 = __builtin_amdgcn_mfma_f32_16x16x32_bf16(a0H, wH0o, C0, 0, 0, 0);
                    C0 = __builtin_amdgcn_mfma_f32_16x16x32_bf16(a0L, wH0o, C0, 0, 0, 0);
                    C0 = __builtin_amdgcn_mfma_f32_16x16x32_bf16(a0H, wL0o, C0, 0, 0, 0);
                    C1 = __builtin_amdgcn_mfma_f32_16x16x32_bf16(a0H, wH1o, C1, 0, 0, 0);
                    C1 = __builtin_amdgcn_mfma_f32_16x16x32_bf16(a0L, wH1o, C1, 0, 0, 0);
                    C1 = __builtin_amdgcn_mfma_f32_16x16x32_bf16(a0H, wL1o, C1, 0, 0, 0);
                }
                float xv[16];
                *(float4*)&xv[0]  = xf0;  *(float4*)&xv[4]  = xf1;
                *(float4*)&xv[8]  = xf2;  *(float4*)&xv[12] = xf3;
#pragma unroll
                for (int kbl = 0; kbl < 2; ++kbl) {
                    short8 aH, aL;
#pragma unroll
                    for (int e = 0; e < 8; ++e) {
                        const float v = xv[kbl * 8 + e];
                        const unsigned short hi = f2bfu(v);
                        aH[e] = (short)hi;
                        aL[e] = (short)f2bfu(v - bfu2f(hi));
                    }
                    const int wo = (16 + kbl) * 512 + lane * 8;
                    const short8 wH0 = *(const short8*)&wgt[wo];
                    const short8 wL0 = *(const short8*)&wgt[32768 + wo];
                    const short8 wH1 = *(const short8*)&wgt[16384 + wo];
                    const short8 wL1 = *(const short8*)&wgt[49152 + wo];
                    C0 = __builtin_amdgcn_mfma_f32_16x16x32_bf16(aH, wH0, C0, 0, 0, 0);
                    C0 = __builtin_amdgcn_mfma_f32_16x16x32_bf16(aL, wH0, C0, 0, 0, 0);
                    C0 = __builtin_amdgcn_mfma_f32_16x16x32_bf16(aH, wL0, C0, 0, 0, 0);
                    C1 = __builtin_amdgcn_mfma_f32_16x16x32_bf16(aH, wH1, C1, 0, 0, 0);
                    C1 = __builtin_amdgcn_mfma_f32_16x16x32_bf16(aL, wH1, C1, 0, 0, 0);
                    C1 = __builtin_amdgcn_mfma_f32_16x16x32_bf16(aH, wL1, C1, 0, 0, 0);
                }
            }

            xpose(C0);
            xpose(C1);

            // ---- gates -> c,h ; stage h(t) hi/lo into LDS hout (chunked layout) ----
            {
                const float gi = C0[0] + bias0.x;
                const float gf = C0[1] + bias0.y;
                const float gg = C0[2] + bias0.z;
                const float go = C0[3] + bias0.w;
                const float iv = fsigm(gi), fv = fsigm(gf), ov = fsigm(go);
                const float gv = ftanh(gg);
                c0 = fv * c0 + iv * gv;
                const float hv = ov * ftanh(c0);
                const unsigned short hi = f2bfu(hv);
                hout[lbase + u0]        = hi;                       // split 0 (H)
                hout[2048 + lbase + u0] = f2bfu(hv - bfu2f(hi));    // split 1 (L)
            }
            {
                const float gi = C1[0] + bias1.x;
                const float gf = C1[1] + bias1.y;
                const float gg = C1[2] + bias1.z;
                const float go = C1[3] + bias1.w;
                const float iv = fsigm(gi), fv = fsigm(gf), ov = fsigm(go);
                const float gv = ftanh(gg);
                c1 = fv * c1 + iv * gv;
                const float hv = ov * ftanh(c1);
                const unsigned short hi = f2bfu(hv);
                hout[lbase + u0 + 4]        = hi;
                hout[2048 + lbase + u0 + 4] = f2bfu(hv - bfu2f(hi));
            }
            __syncthreads();

            // ---- coalesced write-through store: 32 chunks x 256B, 1 u64/thread ----
            {
                const int c   = tid >> 5;            // 0..31
                const int pos = tid & 31;
                const int split = c >> 4;
                const int bcc   = (c >> 1) & 7;
                const int mtc   = c & 1;
                const size_t goff = ((size_t)(l * 2 + pw) * 8 + bcc) * 16384
                                  + (size_t)((kbC << 1) + mtc) * 512 + (size_t)bqC * 128
                                  + (size_t)pos * 4;
                const unsigned long long val =
                    ((const unsigned long long*)hout)[(c << 5) + pos];
                unsigned long long* dst =
                    (unsigned long long*)((split ? bndL : bndH) + goff);
                __hip_atomic_store(dst, val, __ATOMIC_RELAXED, __HIP_MEMORY_SCOPE_AGENT);
            }
        }

        // ---- zero-wbl2 barrier ----
        if (s != NSTEP - 1) {
            __syncthreads();   // drains vmcnt: write-through stores are AT L3 now
            if (tid == 0) {
                __hip_atomic_fetch_add(bar + ((blk & 7) << 6), 1,
                                       __ATOMIC_RELAXED, __HIP_MEMORY_SCOPE_AGENT);
                const int target = 256 * (s + 1);
                int guard = 0;
                for (;;) {
                    int sum = 0;
#pragma unroll
                    for (int i = 0; i < 8; ++i)
                        sum += __hip_atomic_load(bar + (i << 6), __ATOMIC_RELAXED,
                                                 __HIP_MEMORY_SCOPE_AGENT);
                    if (sum >= target) break;
                    if (++guard > (1 << 20)) break;   // escape hatch
                    __builtin_amdgcn_s_sleep(1);
                }
                __builtin_amdgcn_fence(__ATOMIC_ACQUIRE, "agent");   // buffer_inv only
            }
            __syncthreads();
        }
    }
}

// ---------- MLP head: reads h_3[T-1] (parity 0) from bnd frag layout ----------
__global__ __launch_bounds__(128)
void mlp_head(const unsigned short* __restrict__ bndH, const unsigned short* __restrict__ bndL,
              const float* __restrict__ W1, const float* __restrict__ b1,
              const float* __restrict__ W2, const float* __restrict__ b2,
              const float* __restrict__ W3, const float* __restrict__ b3,
              float* __restrict__ out)
{
    __shared__ float hl[H_];
    __shared__ float a1[128];
    __shared__ float a2[64];
    const int b = blockIdx.x, tid = threadIdx.x;
    {
        const int bc = b >> 5, m = b & 31;
        const int mtt = m >> 4, m16 = m & 15;
        const size_t base = ((size_t)48 + bc) * 16384;   // (3*2+0)*8 + bc
        const int k0 = tid << 2;
        const int kb = k0 >> 5, bq = (k0 >> 3) & 3, kk0 = k0 & 7;
        const size_t eo = base + ((size_t)((kb << 1) + mtt) * 64 + (m16 + (bq << 4))) * 8 + kk0;
        const ushort4 vh = *(const ushort4*)(bndH + eo);
        const ushort4 vl = *(const ushort4*)(bndL + eo);
        hl[k0 + 0] = bfu2f(vh.x) + bfu2f(vl.x);
        hl[k0 + 1] = bfu2f(vh.y) + bfu2f(vl.y);
        hl[k0 + 2] = bfu2f(vh.z) + bfu2f(vl.z);
        hl[k0 + 3] = bfu2f(vh.w) + bfu2f(vl.w);
    }
    __syncthreads();
    {
        float s = b1[tid];
        const float* wr = W1 + (size_t)tid * H_;
        for (int k = 0; k < H_; ++k) s = fmaf(wr[k], hl[k], s);
        a1[tid] = fmaxf(s, 0.f);
    }
    __syncthreads();
    if (tid < 64) {
        float s = b2[tid];
        const float* wr = W2 + (tid << 7);
        for (int k = 0; k < 128; ++k) s = fmaf(wr[k], a1[k], s);
        a2[tid] = fmaxf(s, 0.f);
    }
    __syncthreads();
    if (tid < 64) {
        float v = W3[tid] * a2[tid];
        for (int off = 32; off; off >>= 1) v += __shfl_down(v, off);
        if (tid == 0) out[b] = v + b3[0];
    }
}

extern "C" void kernel_launch(void* const* d_in, const int* in_sizes, int n_in,
                              void* d_out, int out_size, void* d_ws, size_t ws_size,
                              hipStream_t stream)
{
    const float* x    = (const float*)d_in[0];
    const float* Wih0 = (const float*)d_in[1];
    const float* WihR = (const float*)d_in[2];
    const float* Whh  = (const float*)d_in[3];
    const float* bih  = (const float*)d_in[4];
    const float* bhh  = (const float*)d_in[5];
    const float* W1   = (const float*)d_in[6];
    const float* b1   = (const float*)d_in[7];
    const float* W2   = (const float*)d_in[8];
    const float* b2   = (const float*)d_in[9];
    const float* W3   = (const float*)d_in[10];
    const float* b3   = (const float*)d_in[11];
    float* out = (float*)d_out;

    const size_t W0e = (size_t)(H_ + I_) * G_;       // 1,179,648 elems (NKB=18)
    const size_t W1e = (size_t)(2 * H_) * G_;        // 2,097,152 elems (NKB=32)
    const size_t biasE = (size_t)L_ * G_;            // 8192
    const size_t bndE  = (size_t)64 * 16384;         // 1,048,576 elems per split
    const size_t barE  = 8 * 64;                     // 8 shards, 256B apart

    auto align256 = [](size_t v) { return (v + 255) & ~(size_t)255; };
    const size_t need = 2 * align256(W0e * 2) + 6 * align256(W1e * 2)
                      + align256(biasE * 4) + align256(barE * sizeof(int))
                      + 2 * align256(bndE * 2);

    char* ws = (char*)d_ws;
    size_t off = 0;
    auto alloc = [&](size_t bytes) -> void* {
        void* p = ws + off;
        off = align256(off + bytes);
        return p;
    };

    if (ws_size < need) {
        sentinel_fill<<<1, 256, 0, stream>>>(out, -11111.0f);
        return;
    }

    unsigned short* WH0 = (unsigned short*)alloc(W0e * 2);
    unsigned short* WL0 = (unsigned short*)alloc(W0e * 2);
    unsigned short* WH1 = (unsigned short*)alloc(W1e * 2);
    unsigned short* WL1 = (unsigned short*)alloc(W1e * 2);
    unsigned short* WH2 = (unsigned short*)alloc(W1e * 2);
    unsigned short* WL2 = (unsigned short*)alloc(W1e * 2);
    unsigned short* WH3 = (unsigned short*)alloc(W1e * 2);
    unsigned short* WL3 = (unsigned short*)alloc(W1e * 2);
    float* biasR = (float*)alloc(biasE * 4);
    int*   bar   = (int*)alloc(barE * sizeof(int));
    unsigned short* bndH = (unsigned short*)alloc(bndE * 2);
    unsigned short* bndL = (unsigned short*)alloc(bndE * 2);

    const size_t WL_ = (size_t)G_ * H_;
    prep_wtfrag<<<1024, 256, 0, stream>>>(Whh + 0 * WL_, Wih0,           I_, 18, WH0, WL0);
    prep_wtfrag<<<1024, 256, 0, stream>>>(Whh + 1 * WL_, WihR + 0 * WL_, H_, 32, WH1, WL1);
    prep_wtfrag<<<1024, 256, 0, stream>>>(Whh + 2 * WL_, WihR + 1 * WL_, H_, 32, WH2, WL2);
    prep_wtfrag<<<1024, 256, 0, stream>>>(Whh + 3 * WL_, WihR + 2 * WL_, H_, 32, WH3, WL3);
    prep_bias<<<(L_ * G_ + 255) / 256, 256, 0, stream>>>(bih, bhh, biasR);
    (void)hipMemsetAsync(bar, 0, barE * sizeof(int), stream);
    (void)hipMemsetAsync(bndH, 0, bndE * 2, stream);
    (void)hipMemsetAsync(bndL, 0, bndE * 2, stream);

    {
        (void)hipFuncSetAttribute((const void*)lstm_pipe,
                                  hipFuncAttributeMaxDynamicSharedMemorySize, 139264);
        const float* xa = x;
        const unsigned short *a0 = WH0, *a1 = WL0, *a2 = WH1, *a3 = WL1,
                             *a4 = WH2, *a5 = WL2, *a6 = WH3, *a7 = WL3;
        const float* br = biasR;
        unsigned short *bh = bndH, *bl = bndL;
        int* bp = bar;
        void* args[] = { (void*)&xa, (void*)&a0, (void*)&a1, (void*)&a2, (void*)&a3,
                         (void*)&a4, (void*)&a5, (void*)&a6, (void*)&a7,
                         (void*)&br, (void*)&bh, (void*)&bl, (void*)&bp };
        hipError_t rc = hipLaunchCooperativeKernel((void*)lstm_pipe, dim3(256), dim3(1024),
                                                   args, 139264, stream);
        if (rc != hipSuccess) {
            sentinel_fill<<<1, 256, 0, stream>>>(out, -22222.0f);
            return;
        }
    }

    mlp_head<<<256, 128, 0, stream>>>(bndH, bndL, W1, b1, W2, b2, W3, b3, out);
}